// Round 6
// baseline (1813.640 us; speedup 1.0000x reference)
//
#include <hip/hip_runtime.h>
#include <hip/hip_bf16.h>

#define D_DIM 1024
#define NTOK 267735
#define NEXT_ 267737   // + 2 cluster columns
#define HEADN 20000

typedef __attribute__((ext_vector_type(8))) short bf16x8;
typedef __attribute__((ext_vector_type(4))) float f32x4;

__device__ __forceinline__ int seg_of(int c){
  if (c < HEADN)  return 0;
  if (c < 20008)  return 1;
  if (c < 20016)  return 2;
  if (c < 200000) return 3;
  if (c < NTOK)   return 4;
  return 0; // cluster columns belong to head softmax
}

__device__ __forceinline__ unsigned pack2(float x, float y){
  __hip_bfloat16 a = __float2bfloat16(x);
  __hip_bfloat16 b = __float2bfloat16(y);
  unsigned short ua = *reinterpret_cast<unsigned short*>(&a);
  unsigned short ub = *reinterpret_cast<unsigned short*>(&b);
  return (unsigned)ua | ((unsigned)ub << 16);
}

#define BM 256
#define BN 128
#define BK 32
#define NTHREADS 512
#define KSTEPS (D_DIM/BK)   // 32
#define NCOLT 2092          // ceil(NEXT_/BN)
#define NBLK 8384           // 8 XCD * 1048 (padded; 16 dead blocks return early)

// LDS layout: [row][32] shorts (64B row). 16B chunk c of row r stored at
// chunk index c ^ ((r>>1)&3): writes conflict-free, b128 frag reads 2-way (free).
// Verified R2/R3/R5: SQ_LDS_BANK_CONFLICT == 0.
__device__ __forceinline__ int swz_w(int r, int k4){   // short offset for 8B write
  int c = (k4 >> 1) ^ ((r >> 1) & 3);
  return r*32 + c*8 + (k4 & 1)*4;
}
__device__ __forceinline__ int swz_r(int row, int q){  // short offset for 16B read
  return row*32 + ((q ^ ((row >> 1) & 3)) << 3);
}

// Per-(row, segment) sum of exp(logit + bias) into accg[row*8 + seg].
// XCD-aware remap (R5-verified: FETCH 2.25 GB -> 0.98 GB): the 4 row-blocks
// sharing one 128-col W strip get bids {b0,b0+8,b0+16,b0+24} -> same XCD.
// K-loop: double-buffered LDS, single prefetch reg set, ONE barrier/K-step.
__global__ __launch_bounds__(NTHREADS, 1) void gemm_lse_kernel(
    const float* __restrict__ hidden, const float* __restrict__ W,
    const float* __restrict__ bias,   const float* __restrict__ cw,
    const float* __restrict__ cb,     float* __restrict__ accg)
{
  const int b = blockIdx.x;
  const int k8 = b & 7;          // XCD slot
  const int sq_ = b >> 3;        // sequence within XCD
  const int xb = sq_ & 3;        // row-block 0..3
  const int yb = (sq_ >> 2) * 8 + k8;  // col-strip
  if (yb >= NCOLT) return;       // 16 pad blocks

  __shared__ unsigned short lsA0[BM * 32];   // 16 KB
  __shared__ unsigned short lsB0[BN * 32];   //  8 KB
  __shared__ unsigned short lsA1[BM * 32];   // 16 KB
  __shared__ unsigned short lsB1[BN * 32];   //  8 KB

  const int tid = threadIdx.x;
  const int rowBase = xb * BM;
  const int colBase = yb * BN;

  // ---- staging assignments (coalesced: 8 lanes cover one row's 32-float k-slab) ----
  const float* aSrc[4]; int aRow[4], aK4[4];
#pragma unroll
  for (int i=0;i<4;++i){
    int idx = tid + NTHREADS*i;            // 0..2047 float4s of A tile
    aRow[i] = idx >> 3; aK4[i] = idx & 7;
    aSrc[i] = hidden + (size_t)(rowBase + aRow[i]) * D_DIM + aK4[i]*4;
  }
  const float* bSrc[2]; int bRow[2], bK4[2];
#pragma unroll
  for (int i=0;i<2;++i){
    int idx = tid + NTHREADS*i;            // 0..1023 float4s of B tile
    bRow[i] = idx >> 3; bK4[i] = idx & 7;
    int c = colBase + bRow[i];
    const float* base;
    if (c < NTOK)       base = W  + (size_t)c * D_DIM;
    else if (c < NEXT_) base = cw + (size_t)(c - NTOK) * D_DIM;
    else                base = W;          // dummy (masked in epilogue)
    bSrc[i] = base + bK4[i]*4;
  }

  const int lane = tid & 63;
  const int wv = tid >> 6;
  const int wm = wv >> 1;   // 0..3 : 64-row slab
  const int wn = wv & 1;    // 0..1 : 64-col slab
  const int q  = lane >> 4; // k-chunk
  const int r16 = lane & 15;

  // precomputed LDS offsets (short-index)
  int wA0 = swz_w(aRow[0], aK4[0]), wA1 = swz_w(aRow[1], aK4[1]);
  int wA2 = swz_w(aRow[2], aK4[2]), wA3 = swz_w(aRow[3], aK4[3]);
  int wB0 = swz_w(bRow[0], bK4[0]), wB1 = swz_w(bRow[1], bK4[1]);
  int rA0 = swz_r(wm*64 +  0 + r16, q), rA1 = swz_r(wm*64 + 16 + r16, q);
  int rA2 = swz_r(wm*64 + 32 + r16, q), rA3 = swz_r(wm*64 + 48 + r16, q);
  int rB0 = swz_r(wn*64 +  0 + r16, q), rB1 = swz_r(wn*64 + 16 + r16, q);
  int rB2 = swz_r(wn*64 + 32 + r16, q), rB3 = swz_r(wn*64 + 48 + r16, q);

  f32x4 acc[4][4];
#pragma unroll
  for (int i=0;i<4;++i)
#pragma unroll
    for (int j=0;j<4;++j) acc[i][j] = (f32x4){0.f,0.f,0.f,0.f};

// named-scalar load/store/mfma (macros: no addressable arrays -> no scratch; R4 lesson)
#define LOADS(kn) \
    va0 = *reinterpret_cast<const float4*>(aSrc[0] + (kn)*BK); \
    va1 = *reinterpret_cast<const float4*>(aSrc[1] + (kn)*BK); \
    va2 = *reinterpret_cast<const float4*>(aSrc[2] + (kn)*BK); \
    va3 = *reinterpret_cast<const float4*>(aSrc[3] + (kn)*BK); \
    vb0 = *reinterpret_cast<const float4*>(bSrc[0] + (kn)*BK); \
    vb1 = *reinterpret_cast<const float4*>(bSrc[1] + (kn)*BK);

#define STORES(LA, LB) { \
    unsigned* p; \
    p = reinterpret_cast<unsigned*>(&LA[wA0]); p[0] = pack2(va0.x, va0.y); p[1] = pack2(va0.z, va0.w); \
    p = reinterpret_cast<unsigned*>(&LA[wA1]); p[0] = pack2(va1.x, va1.y); p[1] = pack2(va1.z, va1.w); \
    p = reinterpret_cast<unsigned*>(&LA[wA2]); p[0] = pack2(va2.x, va2.y); p[1] = pack2(va2.z, va2.w); \
    p = reinterpret_cast<unsigned*>(&LA[wA3]); p[0] = pack2(va3.x, va3.y); p[1] = pack2(va3.z, va3.w); \
    p = reinterpret_cast<unsigned*>(&LB[wB0]); p[0] = pack2(vb0.x, vb0.y); p[1] = pack2(vb0.z, vb0.w); \
    p = reinterpret_cast<unsigned*>(&LB[wB1]); p[0] = pack2(vb1.x, vb1.y); p[1] = pack2(vb1.z, vb1.w); }

#define FRAGS_MFMA(LA, LB) { \
    bf16x8 af0 = *reinterpret_cast<const bf16x8*>(&LA[rA0]); \
    bf16x8 af1 = *reinterpret_cast<const bf16x8*>(&LA[rA1]); \
    bf16x8 af2 = *reinterpret_cast<const bf16x8*>(&LA[rA2]); \
    bf16x8 af3 = *reinterpret_cast<const bf16x8*>(&LA[rA3]); \
    bf16x8 bf0 = *reinterpret_cast<const bf16x8*>(&LB[rB0]); \
    bf16x8 bf1 = *reinterpret_cast<const bf16x8*>(&LB[rB1]); \
    bf16x8 bf2 = *reinterpret_cast<const bf16x8*>(&LB[rB2]); \
    bf16x8 bf3 = *reinterpret_cast<const bf16x8*>(&LB[rB3]); \
    acc[0][0] = __builtin_amdgcn_mfma_f32_16x16x32_bf16(af0, bf0, acc[0][0], 0,0,0); \
    acc[0][1] = __builtin_amdgcn_mfma_f32_16x16x32_bf16(af0, bf1, acc[0][1], 0,0,0); \
    acc[0][2] = __builtin_amdgcn_mfma_f32_16x16x32_bf16(af0, bf2, acc[0][2], 0,0,0); \
    acc[0][3] = __builtin_amdgcn_mfma_f32_16x16x32_bf16(af0, bf3, acc[0][3], 0,0,0); \
    acc[1][0] = __builtin_amdgcn_mfma_f32_16x16x32_bf16(af1, bf0, acc[1][0], 0,0,0); \
    acc[1][1] = __builtin_amdgcn_mfma_f32_16x16x32_bf16(af1, bf1, acc[1][1], 0,0,0); \
    acc[1][2] = __builtin_amdgcn_mfma_f32_16x16x32_bf16(af1, bf2, acc[1][2], 0,0,0); \
    acc[1][3] = __builtin_amdgcn_mfma_f32_16x16x32_bf16(af1, bf3, acc[1][3], 0,0,0); \
    acc[2][0] = __builtin_amdgcn_mfma_f32_16x16x32_bf16(af2, bf0, acc[2][0], 0,0,0); \
    acc[2][1] = __builtin_amdgcn_mfma_f32_16x16x32_bf16(af2, bf1, acc[2][1], 0,0,0); \
    acc[2][2] = __builtin_amdgcn_mfma_f32_16x16x32_bf16(af2, bf2, acc[2][2], 0,0,0); \
    acc[2][3] = __builtin_amdgcn_mfma_f32_16x16x32_bf16(af2, bf3, acc[2][3], 0,0,0); \
    acc[3][0] = __builtin_amdgcn_mfma_f32_16x16x32_bf16(af3, bf0, acc[3][0], 0,0,0); \
    acc[3][1] = __builtin_amdgcn_mfma_f32_16x16x32_bf16(af3, bf1, acc[3][1], 0,0,0); \
    acc[3][2] = __builtin_amdgcn_mfma_f32_16x16x32_bf16(af3, bf2, acc[3][2], 0,0,0); \
    acc[3][3] = __builtin_amdgcn_mfma_f32_16x16x32_bf16(af3, bf3, acc[3][3], 0,0,0); }

  float4 va0, va1, va2, va3, vb0, vb1;

  // prologue: tile 0 -> buf0
  LOADS(0);
  STORES(lsA0, lsB0);
  __syncthreads();

  for (int kt2 = 0; kt2 < KSTEPS/2; ++kt2){
    // ---- phase A: compute tile 2k from buf0; prefetch tile 2k+1 -> buf1 ----
    {
      const int kn = 2*kt2 + 1;
      LOADS(kn);                 // issue-early: latency hides under frags+MFMA
      FRAGS_MFMA(lsA0, lsB0);
      STORES(lsA1, lsB1);        // write-late (vmcnt wait lands here)
      __syncthreads();
    }
    // ---- phase B: compute tile 2k+1 from buf1; prefetch tile 2k+2 -> buf0 ----
    {
      const int kn = 2*kt2 + 2;
      if (kn < KSTEPS){ LOADS(kn); }
      FRAGS_MFMA(lsA1, lsB1);
      if (kn < KSTEPS){ STORES(lsA0, lsB0); __syncthreads(); }
    }
  }

  // ---- fused epilogue: exp + segmented reduce + atomic ----
  int sq[4]; float bq[4];
#pragma unroll
  for (int f=0; f<4; ++f){
    int c = colBase + wn*64 + f*16 + r16;
    if (c < NTOK)       { sq[f] = seg_of(c); bq[f] = bias[c]; }
    else if (c < NEXT_) { sq[f] = 0;         bq[f] = cb[c - NTOK]; }
    else                { sq[f] = -1;        bq[f] = 0.f; }
  }
  int sfirst = seg_of(colBase);
  int clast  = colBase + BN - 1; if (clast > NEXT_-1) clast = NEXT_-1;
  int slast  = seg_of(clast);
  int smin = sfirst, smax = slast;
  if (slast < sfirst){ smin = 0; smax = 4; }   // wrap tile at N_TOKEN boundary

#pragma unroll
  for (int i=0;i<4;++i){
#pragma unroll
    for (int r=0;r<4;++r){
      float e[4];
#pragma unroll
      for (int f=0;f<4;++f) e[f] = __expf(acc[i][f][r] + bq[f]);
      int rowg = rowBase + wm*64 + i*16 + (lane>>4)*4 + r;   // C/D: row=(l>>4)*4+reg
      for (int s2 = smin; s2 <= smax; ++s2){
        float p = 0.f;
#pragma unroll
        for (int f=0;f<4;++f) p += (sq[f]==s2) ? e[f] : 0.f;
#pragma unroll
        for (int off=1; off<16; off<<=1) p += __shfl_xor(p, off, 16);
        if ((lane & 15) == 0 && p != 0.f) atomicAdd(&accg[rowg*8 + s2], p);
      }
    }
  }
}

// One wave per row: target logit + routing logit + final nll.
__global__ __launch_bounds__(256) void finalize_kernel(
    const float* __restrict__ hidden, const int* __restrict__ target,
    const float* __restrict__ W,      const float* __restrict__ bias,
    const float* __restrict__ cw,     const float* __restrict__ cb,
    const float* __restrict__ accg,   float* __restrict__ out)
{
  const int row  = blockIdx.x * 4 + (threadIdx.x >> 6);
  const int lane = threadIdx.x & 63;
  const int t = target[row];

  const float4* h4 = reinterpret_cast<const float4*>(hidden + (size_t)row * D_DIM);
  const float4* w1 = reinterpret_cast<const float4*>(W + (size_t)t * D_DIM);
  int s = 0; const float* jraw = W; float jb = 0.f;
  if (t >= HEADN){
    if      (t < 20008)  { s=1; jraw = W;          jb = bias[0]; }  // j = 0
    else if (t < 20016)  { s=2; jraw = W + D_DIM;  jb = bias[1]; }  // j = 1
    else if (t < 200000) { s=3; jraw = cw + D_DIM; jb = cb[1];   }  // j = 20001 -> cluster 1
    else                 { s=4; jraw = cw;         jb = cb[0];   }  // j = 20000 -> cluster 0
  }
  const float4* w2 = reinterpret_cast<const float4*>(jraw);

  float p1 = 0.f, p2 = 0.f;
#pragma unroll
  for (int j=0;j<4;++j){
    float4 hv = h4[lane + 64*j];
    float4 av = w1[lane + 64*j];
    float4 bv = w2[lane + 64*j];
    p1 += hv.x*av.x + hv.y*av.y + hv.z*av.z + hv.w*av.w;
    p2 += hv.x*bv.x + hv.y*bv.y + hv.z*bv.z + hv.w*bv.w;
  }
#pragma unroll
  for (int off=32; off; off>>=1){
    p1 += __shfl_xor(p1, off, 64);
    p2 += __shfl_xor(p2, off, 64);
  }

  if (lane == 0){
    float lseH = __logf(accg[row*8 + 0]);
    float nll;
    if (t < HEADN){
      nll = -(p1 + bias[t] - lseH);
    } else {
      float lseS = __logf(accg[row*8 + s]);
      nll = -((p2 + jb - lseH) + (p1 + bias[t] - lseS));
    }
    out[row] = nll;
  }
}

extern "C" void kernel_launch(void* const* d_in, const int* in_sizes, int n_in,
                              void* d_out, int out_size, void* d_ws, size_t ws_size,
                              hipStream_t stream)
{
  const float* hidden = (const float*)d_in[0];
  const int*   target = (const int*)  d_in[1];
  const float* W      = (const float*)d_in[2];
  const float* bias   = (const float*)d_in[3];
  const float* cw     = (const float*)d_in[4];
  const float* cb     = (const float*)d_in[5];
  float* out  = (float*)d_out;
  float* accg = (float*)d_ws;          // [1024][8] fp32 sum-of-exp accumulators

  hipMemsetAsync(accg, 0, 1024*8*sizeof(float), stream);

  gemm_lse_kernel<<<NBLK, NTHREADS, 0, stream>>>(hidden, W, bias, cw, cb, accg);
  finalize_kernel<<<256, 256, 0, stream>>>(hidden, target, W, bias, cw, cb, accg, out);
}

// Round 7
// 1059.330 us; speedup vs baseline: 1.7121x; 1.7121x over previous
//
#include <hip/hip_runtime.h>
#include <hip/hip_bf16.h>

#define D_DIM 1024
#define NTOK 267735
#define NEXT_ 267737   // + 2 cluster columns
#define HEADN 20000

typedef __attribute__((ext_vector_type(8))) short bf16x8;
typedef __attribute__((ext_vector_type(4))) float f32x4;

__device__ __forceinline__ int seg_of(int c){
  if (c < HEADN)  return 0;
  if (c < 20008)  return 1;
  if (c < 20016)  return 2;
  if (c < 200000) return 3;
  if (c < NTOK)   return 4;
  return 0; // cluster columns belong to head softmax
}

__device__ __forceinline__ unsigned pack2(float x, float y){
  __hip_bfloat16 a = __float2bfloat16(x);
  __hip_bfloat16 b = __float2bfloat16(y);
  unsigned short ua = *reinterpret_cast<unsigned short*>(&a);
  unsigned short ub = *reinterpret_cast<unsigned short*>(&b);
  return (unsigned)ua | ((unsigned)ub << 16);
}

#define BM 256
#define BN 128
#define BK 32
#define NTHREADS 512
#define KSTEPS (D_DIM/BK)   // 32
#define NCOLT 2092          // ceil(NEXT_/BN)
#define NBLK 8384           // 8 XCD * 1048 (padded; 16 dead blocks return early)

// LDS layout: [row][32] shorts (64B row). 16B chunk c of row r stored at
// chunk index c ^ ((r>>1)&3): writes conflict-free, b128 frag reads 2-way (free).
// Verified R2/R3/R5: SQ_LDS_BANK_CONFLICT == 0.
__device__ __forceinline__ int swz_w(int r, int k4){   // short offset for 8B write
  int c = (k4 >> 1) ^ ((r >> 1) & 3);
  return r*32 + c*8 + (k4 & 1)*4;
}
__device__ __forceinline__ int swz_r(int row, int q){  // short offset for 16B read
  return row*32 + ((q ^ ((row >> 1) & 3)) << 3);
}

// Per-(row, segment) sum of exp(logit + bias) into accg[row*8 + seg].
// Operating point: 1 block/CU (launch_bounds(512,2) -> 256-reg budget), so
// depth-2 prefetch registers are free. Double-buffered LDS, ONE barrier per
// K-step, loads for tile k+2 issued at step k (store waits a counted vmcnt
// that is a full K-step old -> latency covered). XCD remap kept (R5: FETCH
// 2.25 GB -> 0.98 GB).
__global__ __launch_bounds__(NTHREADS, 2) void gemm_lse_kernel(
    const float* __restrict__ hidden, const float* __restrict__ W,
    const float* __restrict__ bias,   const float* __restrict__ cw,
    const float* __restrict__ cb,     float* __restrict__ accg)
{
  const int b = blockIdx.x;
  const int k8 = b & 7;          // XCD slot
  const int sq_ = b >> 3;        // sequence within XCD
  const int xb = sq_ & 3;        // row-block 0..3
  const int yb = (sq_ >> 2) * 8 + k8;  // col-strip
  if (yb >= NCOLT) return;       // 16 pad blocks

  __shared__ unsigned short lsA0[BM * 32];   // 16 KB
  __shared__ unsigned short lsB0[BN * 32];   //  8 KB
  __shared__ unsigned short lsA1[BM * 32];   // 16 KB
  __shared__ unsigned short lsB1[BN * 32];   //  8 KB

  const int tid = threadIdx.x;
  const int rowBase = xb * BM;
  const int colBase = yb * BN;

  // ---- staging assignments (coalesced: 8 lanes cover one row's 32-float k-slab) ----
  const float* aSrc[4]; int aRow[4], aK4[4];
#pragma unroll
  for (int i=0;i<4;++i){
    int idx = tid + NTHREADS*i;            // 0..2047 float4s of A tile
    aRow[i] = idx >> 3; aK4[i] = idx & 7;
    aSrc[i] = hidden + (size_t)(rowBase + aRow[i]) * D_DIM + aK4[i]*4;
  }
  const float* bSrc[2]; int bRow[2], bK4[2];
#pragma unroll
  for (int i=0;i<2;++i){
    int idx = tid + NTHREADS*i;            // 0..1023 float4s of B tile
    bRow[i] = idx >> 3; bK4[i] = idx & 7;
    int c = colBase + bRow[i];
    const float* base;
    if (c < NTOK)       base = W  + (size_t)c * D_DIM;
    else if (c < NEXT_) base = cw + (size_t)(c - NTOK) * D_DIM;
    else                base = W;          // dummy (masked in epilogue)
    bSrc[i] = base + bK4[i]*4;
  }

  const int lane = tid & 63;
  const int wv = tid >> 6;
  const int wm = wv >> 1;   // 0..3 : 64-row slab
  const int wn = wv & 1;    // 0..1 : 64-col slab
  const int q  = lane >> 4; // k-chunk
  const int r16 = lane & 15;

  // precomputed LDS offsets (short-index)
  int wA0 = swz_w(aRow[0], aK4[0]), wA1 = swz_w(aRow[1], aK4[1]);
  int wA2 = swz_w(aRow[2], aK4[2]), wA3 = swz_w(aRow[3], aK4[3]);
  int wB0 = swz_w(bRow[0], bK4[0]), wB1 = swz_w(bRow[1], bK4[1]);
  int rA0 = swz_r(wm*64 +  0 + r16, q), rA1 = swz_r(wm*64 + 16 + r16, q);
  int rA2 = swz_r(wm*64 + 32 + r16, q), rA3 = swz_r(wm*64 + 48 + r16, q);
  int rB0 = swz_r(wn*64 +  0 + r16, q), rB1 = swz_r(wn*64 + 16 + r16, q);
  int rB2 = swz_r(wn*64 + 32 + r16, q), rB3 = swz_r(wn*64 + 48 + r16, q);

  f32x4 acc[4][4];
#pragma unroll
  for (int i=0;i<4;++i)
#pragma unroll
    for (int j=0;j<4;++j) acc[i][j] = (f32x4){0.f,0.f,0.f,0.f};

  // two named prefetch sets (no addressable arrays -> no scratch; R4 lesson)
  float4 s0a0, s0a1, s0a2, s0a3, s0b0, s0b1;
  float4 s1a0, s1a1, s1a2, s1a3, s1b0, s1b1;

#define LOADS_S0(kn) \
    s0a0 = *reinterpret_cast<const float4*>(aSrc[0] + (kn)*BK); \
    s0a1 = *reinterpret_cast<const float4*>(aSrc[1] + (kn)*BK); \
    s0a2 = *reinterpret_cast<const float4*>(aSrc[2] + (kn)*BK); \
    s0a3 = *reinterpret_cast<const float4*>(aSrc[3] + (kn)*BK); \
    s0b0 = *reinterpret_cast<const float4*>(bSrc[0] + (kn)*BK); \
    s0b1 = *reinterpret_cast<const float4*>(bSrc[1] + (kn)*BK);

#define LOADS_S1(kn) \
    s1a0 = *reinterpret_cast<const float4*>(aSrc[0] + (kn)*BK); \
    s1a1 = *reinterpret_cast<const float4*>(aSrc[1] + (kn)*BK); \
    s1a2 = *reinterpret_cast<const float4*>(aSrc[2] + (kn)*BK); \
    s1a3 = *reinterpret_cast<const float4*>(aSrc[3] + (kn)*BK); \
    s1b0 = *reinterpret_cast<const float4*>(bSrc[0] + (kn)*BK); \
    s1b1 = *reinterpret_cast<const float4*>(bSrc[1] + (kn)*BK);

#define STORES_S0(LA, LB) { \
    unsigned* p; \
    p = reinterpret_cast<unsigned*>(&LA[wA0]); p[0] = pack2(s0a0.x, s0a0.y); p[1] = pack2(s0a0.z, s0a0.w); \
    p = reinterpret_cast<unsigned*>(&LA[wA1]); p[0] = pack2(s0a1.x, s0a1.y); p[1] = pack2(s0a1.z, s0a1.w); \
    p = reinterpret_cast<unsigned*>(&LA[wA2]); p[0] = pack2(s0a2.x, s0a2.y); p[1] = pack2(s0a2.z, s0a2.w); \
    p = reinterpret_cast<unsigned*>(&LA[wA3]); p[0] = pack2(s0a3.x, s0a3.y); p[1] = pack2(s0a3.z, s0a3.w); \
    p = reinterpret_cast<unsigned*>(&LB[wB0]); p[0] = pack2(s0b0.x, s0b0.y); p[1] = pack2(s0b0.z, s0b0.w); \
    p = reinterpret_cast<unsigned*>(&LB[wB1]); p[0] = pack2(s0b1.x, s0b1.y); p[1] = pack2(s0b1.z, s0b1.w); }

#define STORES_S1(LA, LB) { \
    unsigned* p; \
    p = reinterpret_cast<unsigned*>(&LA[wA0]); p[0] = pack2(s1a0.x, s1a0.y); p[1] = pack2(s1a0.z, s1a0.w); \
    p = reinterpret_cast<unsigned*>(&LA[wA1]); p[0] = pack2(s1a1.x, s1a1.y); p[1] = pack2(s1a1.z, s1a1.w); \
    p = reinterpret_cast<unsigned*>(&LA[wA2]); p[0] = pack2(s1a2.x, s1a2.y); p[1] = pack2(s1a2.z, s1a2.w); \
    p = reinterpret_cast<unsigned*>(&LA[wA3]); p[0] = pack2(s1a3.x, s1a3.y); p[1] = pack2(s1a3.z, s1a3.w); \
    p = reinterpret_cast<unsigned*>(&LB[wB0]); p[0] = pack2(s1b0.x, s1b0.y); p[1] = pack2(s1b0.z, s1b0.w); \
    p = reinterpret_cast<unsigned*>(&LB[wB1]); p[0] = pack2(s1b1.x, s1b1.y); p[1] = pack2(s1b1.z, s1b1.w); }

#define FRAGS_MFMA(LA, LB) { \
    bf16x8 af0 = *reinterpret_cast<const bf16x8*>(&LA[rA0]); \
    bf16x8 af1 = *reinterpret_cast<const bf16x8*>(&LA[rA1]); \
    bf16x8 af2 = *reinterpret_cast<const bf16x8*>(&LA[rA2]); \
    bf16x8 af3 = *reinterpret_cast<const bf16x8*>(&LA[rA3]); \
    bf16x8 bf0 = *reinterpret_cast<const bf16x8*>(&LB[rB0]); \
    bf16x8 bf1 = *reinterpret_cast<const bf16x8*>(&LB[rB1]); \
    bf16x8 bf2 = *reinterpret_cast<const bf16x8*>(&LB[rB2]); \
    bf16x8 bf3 = *reinterpret_cast<const bf16x8*>(&LB[rB3]); \
    acc[0][0] = __builtin_amdgcn_mfma_f32_16x16x32_bf16(af0, bf0, acc[0][0], 0,0,0); \
    acc[0][1] = __builtin_amdgcn_mfma_f32_16x16x32_bf16(af0, bf1, acc[0][1], 0,0,0); \
    acc[0][2] = __builtin_amdgcn_mfma_f32_16x16x32_bf16(af0, bf2, acc[0][2], 0,0,0); \
    acc[0][3] = __builtin_amdgcn_mfma_f32_16x16x32_bf16(af0, bf3, acc[0][3], 0,0,0); \
    acc[1][0] = __builtin_amdgcn_mfma_f32_16x16x32_bf16(af1, bf0, acc[1][0], 0,0,0); \
    acc[1][1] = __builtin_amdgcn_mfma_f32_16x16x32_bf16(af1, bf1, acc[1][1], 0,0,0); \
    acc[1][2] = __builtin_amdgcn_mfma_f32_16x16x32_bf16(af1, bf2, acc[1][2], 0,0,0); \
    acc[1][3] = __builtin_amdgcn_mfma_f32_16x16x32_bf16(af1, bf3, acc[1][3], 0,0,0); \
    acc[2][0] = __builtin_amdgcn_mfma_f32_16x16x32_bf16(af2, bf0, acc[2][0], 0,0,0); \
    acc[2][1] = __builtin_amdgcn_mfma_f32_16x16x32_bf16(af2, bf1, acc[2][1], 0,0,0); \
    acc[2][2] = __builtin_amdgcn_mfma_f32_16x16x32_bf16(af2, bf2, acc[2][2], 0,0,0); \
    acc[2][3] = __builtin_amdgcn_mfma_f32_16x16x32_bf16(af2, bf3, acc[2][3], 0,0,0); \
    acc[3][0] = __builtin_amdgcn_mfma_f32_16x16x32_bf16(af3, bf0, acc[3][0], 0,0,0); \
    acc[3][1] = __builtin_amdgcn_mfma_f32_16x16x32_bf16(af3, bf1, acc[3][1], 0,0,0); \
    acc[3][2] = __builtin_amdgcn_mfma_f32_16x16x32_bf16(af3, bf2, acc[3][2], 0,0,0); \
    acc[3][3] = __builtin_amdgcn_mfma_f32_16x16x32_bf16(af3, bf3, acc[3][3], 0,0,0); }

  // prologue: tiles 0 and 1 in flight; tile 0 -> buf0
  LOADS_S0(0);
  LOADS_S1(1);
  STORES_S0(lsA0, lsB0);   // counted vmcnt: waits only set0, set1 stays in flight
  __syncthreads();

  for (int kt2 = 0; kt2 < KSTEPS/2; ++kt2){
    // ---- even step: buf0 = tile 2k; set1 = tile 2k+1 (one step old) ----
    {
      const int kn = 2*kt2 + 2;
      if (kn < KSTEPS){ LOADS_S0(kn); }     // issue tile 2k+2
      FRAGS_MFMA(lsA0, lsB0);
      STORES_S1(lsA1, lsB1);                // tile 2k+1; its loads are a full step old
      __syncthreads();
    }
    // ---- odd step: buf1 = tile 2k+1; set0 = tile 2k+2 (one step old) ----
    {
      const int kn = 2*kt2 + 3;
      if (kn < KSTEPS){ LOADS_S1(kn); }     // issue tile 2k+3
      FRAGS_MFMA(lsA1, lsB1);
      if (2*kt2 + 2 < KSTEPS){
        STORES_S0(lsA0, lsB0);              // tile 2k+2
        __syncthreads();
      }
    }
  }

  // ---- fused epilogue: exp + segmented reduce + atomic ----
  int sq[4]; float bq[4];
#pragma unroll
  for (int f=0; f<4; ++f){
    int c = colBase + wn*64 + f*16 + r16;
    if (c < NTOK)       { sq[f] = seg_of(c); bq[f] = bias[c]; }
    else if (c < NEXT_) { sq[f] = 0;         bq[f] = cb[c - NTOK]; }
    else                { sq[f] = -1;        bq[f] = 0.f; }
  }
  int sfirst = seg_of(colBase);
  int clast  = colBase + BN - 1; if (clast > NEXT_-1) clast = NEXT_-1;
  int slast  = seg_of(clast);
  int smin = sfirst, smax = slast;
  if (slast < sfirst){ smin = 0; smax = 4; }   // wrap tile at N_TOKEN boundary

#pragma unroll
  for (int i=0;i<4;++i){
#pragma unroll
    for (int r=0;r<4;++r){
      float e[4];
#pragma unroll
      for (int f=0;f<4;++f) e[f] = __expf(acc[i][f][r] + bq[f]);
      int rowg = rowBase + wm*64 + i*16 + (lane>>4)*4 + r;   // C/D: row=(l>>4)*4+reg
      for (int s2 = smin; s2 <= smax; ++s2){
        float p = 0.f;
#pragma unroll
        for (int f=0;f<4;++f) p += (sq[f]==s2) ? e[f] : 0.f;
#pragma unroll
        for (int off=1; off<16; off<<=1) p += __shfl_xor(p, off, 16);
        if ((lane & 15) == 0 && p != 0.f) atomicAdd(&accg[rowg*8 + s2], p);
      }
    }
  }
}

// One wave per row: target logit + routing logit + final nll.
__global__ __launch_bounds__(256) void finalize_kernel(
    const float* __restrict__ hidden, const int* __restrict__ target,
    const float* __restrict__ W,      const float* __restrict__ bias,
    const float* __restrict__ cw,     const float* __restrict__ cb,
    const float* __restrict__ accg,   float* __restrict__ out)
{
  const int row  = blockIdx.x * 4 + (threadIdx.x >> 6);
  const int lane = threadIdx.x & 63;
  const int t = target[row];

  const float4* h4 = reinterpret_cast<const float4*>(hidden + (size_t)row * D_DIM);
  const float4* w1 = reinterpret_cast<const float4*>(W + (size_t)t * D_DIM);
  int s = 0; const float* jraw = W; float jb = 0.f;
  if (t >= HEADN){
    if      (t < 20008)  { s=1; jraw = W;          jb = bias[0]; }  // j = 0
    else if (t < 20016)  { s=2; jraw = W + D_DIM;  jb = bias[1]; }  // j = 1
    else if (t < 200000) { s=3; jraw = cw + D_DIM; jb = cb[1];   }  // j = 20001 -> cluster 1
    else                 { s=4; jraw = cw;         jb = cb[0];   }  // j = 20000 -> cluster 0
  }
  const float4* w2 = reinterpret_cast<const float4*>(jraw);

  float p1 = 0.f, p2 = 0.f;
#pragma unroll
  for (int j=0;j<4;++j){
    float4 hv = h4[lane + 64*j];
    float4 av = w1[lane + 64*j];
    float4 bv = w2[lane + 64*j];
    p1 += hv.x*av.x + hv.y*av.y + hv.z*av.z + hv.w*av.w;
    p2 += hv.x*bv.x + hv.y*bv.y + hv.z*bv.z + hv.w*bv.w;
  }
#pragma unroll
  for (int off=32; off; off>>=1){
    p1 += __shfl_xor(p1, off, 64);
    p2 += __shfl_xor(p2, off, 64);
  }

  if (lane == 0){
    float lseH = __logf(accg[row*8 + 0]);
    float nll;
    if (t < HEADN){
      nll = -(p1 + bias[t] - lseH);
    } else {
      float lseS = __logf(accg[row*8 + s]);
      nll = -((p2 + jb - lseH) + (p1 + bias[t] - lseS));
    }
    out[row] = nll;
  }
}

extern "C" void kernel_launch(void* const* d_in, const int* in_sizes, int n_in,
                              void* d_out, int out_size, void* d_ws, size_t ws_size,
                              hipStream_t stream)
{
  const float* hidden = (const float*)d_in[0];
  const int*   target = (const int*)  d_in[1];
  const float* W      = (const float*)d_in[2];
  const float* bias   = (const float*)d_in[3];
  const float* cw     = (const float*)d_in[4];
  const float* cb     = (const float*)d_in[5];
  float* out  = (float*)d_out;
  float* accg = (float*)d_ws;          // [1024][8] fp32 sum-of-exp accumulators

  hipMemsetAsync(accg, 0, 1024*8*sizeof(float), stream);

  gemm_lse_kernel<<<NBLK, NTHREADS, 0, stream>>>(hidden, W, bias, cw, cb, accg);
  finalize_kernel<<<256, 256, 0, stream>>>(hidden, target, W, bias, cw, cb, accg, out);
}

// Round 8
// 939.580 us; speedup vs baseline: 1.9303x; 1.1275x over previous
//
#include <hip/hip_runtime.h>
#include <hip/hip_bf16.h>

#define D_DIM 1024
#define NTOK 267735
#define NEXT_ 267737   // + 2 cluster columns
#define HEADN 20000

typedef __attribute__((ext_vector_type(8))) short bf16x8;
typedef __attribute__((ext_vector_type(4))) float f32x4;

__device__ __forceinline__ int seg_of(int c){
  if (c < HEADN)  return 0;
  if (c < 20008)  return 1;
  if (c < 20016)  return 2;
  if (c < 200000) return 3;
  if (c < NTOK)   return 4;
  return 0; // cluster columns belong to head softmax
}

__device__ __forceinline__ unsigned pack2(float x, float y){
  __hip_bfloat16 a = __float2bfloat16(x);
  __hip_bfloat16 b = __float2bfloat16(y);
  unsigned short ua = *reinterpret_cast<unsigned short*>(&a);
  unsigned short ub = *reinterpret_cast<unsigned short*>(&b);
  return (unsigned)ua | ((unsigned)ub << 16);
}

#define BM 256
#define BN 128
#define BK 32
#define NTHREADS 512
#define KSTEPS (D_DIM/BK)   // 32
#define NCOLT 2092          // ceil(NEXT_/BN)
#define NBLK 8384           // 8 XCD * 1048 (padded; 16 dead blocks return early)

#define APRIME_OFF 32768                      // byte offset of A' in ws
#define APRIME_BYTES (1024*1024*2)            // 2 MB bf16 fragment-ordered hidden

// LDS layout for B: [row][32] shorts (64B row). 16B chunk c of row r stored at
// chunk index c ^ ((r>>1)&3): writes conflict-free, b128 frag reads 2-way (free).
// Verified R2/R3/R5: SQ_LDS_BANK_CONFLICT == 0.
__device__ __forceinline__ int swz_w(int r, int k4){   // short offset for 8B write
  int c = (k4 >> 1) ^ ((r >> 1) & 3);
  return r*32 + c*8 + (k4 & 1)*4;
}
__device__ __forceinline__ int swz_r(int row, int q){  // short offset for 16B read
  return row*32 + ((q ^ ((row >> 1) & 3)) << 3);
}

// Convert hidden (1024x1024 f32) -> A' bf16 in MFMA-fragment order:
// A'[rb(64)][kc(128)][r16(16)][e(8)], element (row,k) at rb=row/16, kc=k/8,
// r16=row%16, e=k%8. A wave's frag load (lane l: q=l>>4, r16=l&15) is then
// 1024 contiguous bytes -> perfectly coalesced global b128s, L2-resident.
__global__ void prep_convert(const float* __restrict__ hidden,
                             unsigned short* __restrict__ Ap)
{
  int t = blockIdx.x * blockDim.x + threadIdx.x;   // 0..131071
  int r16 = t & 15, kc = (t >> 4) & 127, rb = t >> 11;
  const float4* src = reinterpret_cast<const float4*>(hidden + ((size_t)(rb*16 + r16) * D_DIM + kc*8));
  float4 x = src[0], y = src[1];
  uint4 o;
  o.x = pack2(x.x, x.y); o.y = pack2(x.z, x.w);
  o.z = pack2(y.x, y.y); o.w = pack2(y.z, y.w);
  reinterpret_cast<uint4*>(Ap)[t] = o;             // dst = t*16B: fully coalesced
}

// Per-(row, segment) sum of exp(logit + bias) into accg[row*8 + seg].
// A read direct-from-global in fragment order (no LDS, no in-loop cvt);
// B double-buffered in LDS (2x8KB), issue-early / write-late, ONE barrier
// per K-step. XCD remap kept (R5: FETCH 2.25 GB -> 0.98 GB).
// Operating point: <=64 arch VGPR -> 2 blocks/CU (R5 lesson).
__global__ __launch_bounds__(NTHREADS, 1) void gemm_lse_adir(
    const unsigned short* __restrict__ Ap, const float* __restrict__ W,
    const float* __restrict__ bias,   const float* __restrict__ cw,
    const float* __restrict__ cb,     float* __restrict__ accg)
{
  const int b = blockIdx.x;
  const int k8 = b & 7;          // XCD slot
  const int sq_ = b >> 3;        // sequence within XCD
  const int xb = sq_ & 3;        // row-block 0..3
  const int yb = (sq_ >> 2) * 8 + k8;  // col-strip
  if (yb >= NCOLT) return;       // 16 pad blocks

  __shared__ unsigned short lsB0[BN * 32];   // 8 KB
  __shared__ unsigned short lsB1[BN * 32];   // 8 KB

  const int tid = threadIdx.x;
  const int rowBase = xb * BM;
  const int colBase = yb * BN;

  // ---- B staging assignments (8 lanes cover one row's 32-float k-slab) ----
  const float* bSrc[2]; int bRow[2], bK4[2];
#pragma unroll
  for (int i=0;i<2;++i){
    int idx = tid + NTHREADS*i;            // 0..1023 float4s of B tile
    bRow[i] = idx >> 3; bK4[i] = idx & 7;
    int c = colBase + bRow[i];
    const float* base;
    if (c < NTOK)       base = W  + (size_t)c * D_DIM;
    else if (c < NEXT_) base = cw + (size_t)(c - NTOK) * D_DIM;
    else                base = W;          // dummy (masked in epilogue)
    bSrc[i] = base + bK4[i]*4;
  }

  const int lane = tid & 63;
  const int wv = tid >> 6;
  const int wm = wv >> 1;   // 0..3 : 64-row slab
  const int wn = wv & 1;    // 0..1 : 64-col slab
  const int q  = lane >> 4; // k-chunk
  const int r16 = lane & 15;

  const int wB0 = swz_w(bRow[0], bK4[0]), wB1 = swz_w(bRow[1], bK4[1]);
  const int rB0 = swz_r(wn*64 +  0 + r16, q), rB1 = swz_r(wn*64 + 16 + r16, q);
  const int rB2 = swz_r(wn*64 + 32 + r16, q), rB3 = swz_r(wn*64 + 48 + r16, q);

  // A' fragment pointers: frag f covers rows rowBase + f*16.. (wave wm slab)
  // ushort idx = (xb*16 + wm*4 + f)*16384 + (kt*4+q)*128 + r16*8
  const unsigned short* a0 = Ap + (size_t)(xb*16 + wm*4 + 0)*16384 + q*128 + r16*8;
  const unsigned short* a1 = Ap + (size_t)(xb*16 + wm*4 + 1)*16384 + q*128 + r16*8;
  const unsigned short* a2 = Ap + (size_t)(xb*16 + wm*4 + 2)*16384 + q*128 + r16*8;
  const unsigned short* a3 = Ap + (size_t)(xb*16 + wm*4 + 3)*16384 + q*128 + r16*8;

  f32x4 acc[4][4];
#pragma unroll
  for (int i=0;i<4;++i)
#pragma unroll
    for (int j=0;j<4;++j) acc[i][j] = (f32x4){0.f,0.f,0.f,0.f};

  // prologue: B tile 0 -> buf0
  {
    float4 v0 = *reinterpret_cast<const float4*>(bSrc[0]);
    float4 v1 = *reinterpret_cast<const float4*>(bSrc[1]);
    unsigned* p;
    p = reinterpret_cast<unsigned*>(&lsB0[wB0]); p[0] = pack2(v0.x, v0.y); p[1] = pack2(v0.z, v0.w);
    p = reinterpret_cast<unsigned*>(&lsB0[wB1]); p[0] = pack2(v1.x, v1.y); p[1] = pack2(v1.z, v1.w);
  }
  __syncthreads();

#pragma unroll 2
  for (int kt = 0; kt < KSTEPS; ++kt){
    unsigned short* Lr = (kt & 1) ? lsB1 : lsB0;   // compute buffer
    unsigned short* Lw = (kt & 1) ? lsB0 : lsB1;   // next-tile buffer
    const bool havenext = (kt + 1 < KSTEPS);

    // issue-early: next B tile (8 regs live across MFMA phase)
    float4 nb0, nb1;
    if (havenext){
      nb0 = *reinterpret_cast<const float4*>(bSrc[0] + (kt+1)*BK);
      nb1 = *reinterpret_cast<const float4*>(bSrc[1] + (kt+1)*BK);
    }

    // A fragments direct from global (coalesced 1024B/wave each)
    bf16x8 af0 = *reinterpret_cast<const bf16x8*>(a0 + kt*512);
    bf16x8 af1 = *reinterpret_cast<const bf16x8*>(a1 + kt*512);
    bf16x8 af2 = *reinterpret_cast<const bf16x8*>(a2 + kt*512);
    bf16x8 af3 = *reinterpret_cast<const bf16x8*>(a3 + kt*512);

    // B fragments from LDS
    bf16x8 bf0 = *reinterpret_cast<const bf16x8*>(&Lr[rB0]);
    bf16x8 bf1 = *reinterpret_cast<const bf16x8*>(&Lr[rB1]);
    bf16x8 bf2 = *reinterpret_cast<const bf16x8*>(&Lr[rB2]);
    bf16x8 bf3 = *reinterpret_cast<const bf16x8*>(&Lr[rB3]);

    acc[0][0] = __builtin_amdgcn_mfma_f32_16x16x32_bf16(af0, bf0, acc[0][0], 0,0,0);
    acc[0][1] = __builtin_amdgcn_mfma_f32_16x16x32_bf16(af0, bf1, acc[0][1], 0,0,0);
    acc[0][2] = __builtin_amdgcn_mfma_f32_16x16x32_bf16(af0, bf2, acc[0][2], 0,0,0);
    acc[0][3] = __builtin_amdgcn_mfma_f32_16x16x32_bf16(af0, bf3, acc[0][3], 0,0,0);
    acc[1][0] = __builtin_amdgcn_mfma_f32_16x16x32_bf16(af1, bf0, acc[1][0], 0,0,0);
    acc[1][1] = __builtin_amdgcn_mfma_f32_16x16x32_bf16(af1, bf1, acc[1][1], 0,0,0);
    acc[1][2] = __builtin_amdgcn_mfma_f32_16x16x32_bf16(af1, bf2, acc[1][2], 0,0,0);
    acc[1][3] = __builtin_amdgcn_mfma_f32_16x16x32_bf16(af1, bf3, acc[1][3], 0,0,0);
    acc[2][0] = __builtin_amdgcn_mfma_f32_16x16x32_bf16(af2, bf0, acc[2][0], 0,0,0);
    acc[2][1] = __builtin_amdgcn_mfma_f32_16x16x32_bf16(af2, bf1, acc[2][1], 0,0,0);
    acc[2][2] = __builtin_amdgcn_mfma_f32_16x16x32_bf16(af2, bf2, acc[2][2], 0,0,0);
    acc[2][3] = __builtin_amdgcn_mfma_f32_16x16x32_bf16(af2, bf3, acc[2][3], 0,0,0);
    acc[3][0] = __builtin_amdgcn_mfma_f32_16x16x32_bf16(af3, bf0, acc[3][0], 0,0,0);
    acc[3][1] = __builtin_amdgcn_mfma_f32_16x16x32_bf16(af3, bf1, acc[3][1], 0,0,0);
    acc[3][2] = __builtin_amdgcn_mfma_f32_16x16x32_bf16(af3, bf2, acc[3][2], 0,0,0);
    acc[3][3] = __builtin_amdgcn_mfma_f32_16x16x32_bf16(af3, bf3, acc[3][3], 0,0,0);

    // write-late: next B tile into the other buffer (its previous readers
    // finished before the preceding barrier -> one barrier per step is safe)
    if (havenext){
      unsigned* p;
      p = reinterpret_cast<unsigned*>(&Lw[wB0]); p[0] = pack2(nb0.x, nb0.y); p[1] = pack2(nb0.z, nb0.w);
      p = reinterpret_cast<unsigned*>(&Lw[wB1]); p[0] = pack2(nb1.x, nb1.y); p[1] = pack2(nb1.z, nb1.w);
    }
    __syncthreads();
  }

  // ---- fused epilogue: exp + segmented reduce + atomic ----
  int sq[4]; float bq[4];
#pragma unroll
  for (int f=0; f<4; ++f){
    int c = colBase + wn*64 + f*16 + r16;
    if (c < NTOK)       { sq[f] = seg_of(c); bq[f] = bias[c]; }
    else if (c < NEXT_) { sq[f] = 0;         bq[f] = cb[c - NTOK]; }
    else                { sq[f] = -1;        bq[f] = 0.f; }
  }
  int sfirst = seg_of(colBase);
  int clast  = colBase + BN - 1; if (clast > NEXT_-1) clast = NEXT_-1;
  int slast  = seg_of(clast);
  int smin = sfirst, smax = slast;
  if (slast < sfirst){ smin = 0; smax = 4; }   // wrap tile at N_TOKEN boundary

#pragma unroll
  for (int i=0;i<4;++i){
#pragma unroll
    for (int r=0;r<4;++r){
      float e[4];
#pragma unroll
      for (int f=0;f<4;++f) e[f] = __expf(acc[i][f][r] + bq[f]);
      int rowg = rowBase + wm*64 + i*16 + (lane>>4)*4 + r;   // C/D: row=(l>>4)*4+reg
      for (int s2 = smin; s2 <= smax; ++s2){
        float p = 0.f;
#pragma unroll
        for (int f=0;f<4;++f) p += (sq[f]==s2) ? e[f] : 0.f;
#pragma unroll
        for (int off=1; off<16; off<<=1) p += __shfl_xor(p, off, 16);
        if ((lane & 15) == 0 && p != 0.f) atomicAdd(&accg[rowg*8 + s2], p);
      }
    }
  }
}

// ---------------- R5 fallback (used only if ws too small for A') ----------------
__global__ __launch_bounds__(NTHREADS, 1) void gemm_lse_fb(
    const float* __restrict__ hidden, const float* __restrict__ W,
    const float* __restrict__ bias,   const float* __restrict__ cw,
    const float* __restrict__ cb,     float* __restrict__ accg)
{
  const int b = blockIdx.x;
  const int k8 = b & 7;
  const int sq_ = b >> 3;
  const int xb = sq_ & 3;
  const int yb = (sq_ >> 2) * 8 + k8;
  if (yb >= NCOLT) return;

  __shared__ unsigned short lsA[BM * 32];
  __shared__ unsigned short lsB[BN * 32];

  const int tid = threadIdx.x;
  const int rowBase = xb * BM;
  const int colBase = yb * BN;

  const float* aSrc[4]; int aRow[4], aK4[4];
#pragma unroll
  for (int i=0;i<4;++i){
    int idx = tid + NTHREADS*i;
    aRow[i] = idx >> 3; aK4[i] = idx & 7;
    aSrc[i] = hidden + (size_t)(rowBase + aRow[i]) * D_DIM + aK4[i]*4;
  }
  const float* bSrc[2]; int bRow[2], bK4[2];
#pragma unroll
  for (int i=0;i<2;++i){
    int idx = tid + NTHREADS*i;
    bRow[i] = idx >> 3; bK4[i] = idx & 7;
    int c = colBase + bRow[i];
    const float* base;
    if (c < NTOK)       base = W  + (size_t)c * D_DIM;
    else if (c < NEXT_) base = cw + (size_t)(c - NTOK) * D_DIM;
    else                base = W;
    bSrc[i] = base + bK4[i]*4;
  }

  const int lane = tid & 63;
  const int wv = tid >> 6;
  const int wm = wv >> 1;
  const int wn = wv & 1;
  const int q  = lane >> 4;
  const int r16 = lane & 15;

  f32x4 acc[4][4];
#pragma unroll
  for (int i=0;i<4;++i)
#pragma unroll
    for (int j=0;j<4;++j) acc[i][j] = (f32x4){0.f,0.f,0.f,0.f};

  for (int kt = 0; kt < KSTEPS; ++kt){
    float4 av[4], bv[2];
#pragma unroll
    for (int i=0;i<4;++i) av[i] = *reinterpret_cast<const float4*>(aSrc[i] + kt*BK);
#pragma unroll
    for (int i=0;i<2;++i) bv[i] = *reinterpret_cast<const float4*>(bSrc[i] + kt*BK);
    __syncthreads();
#pragma unroll
    for (int i=0;i<4;++i){
      unsigned* p = reinterpret_cast<unsigned*>(&lsA[swz_w(aRow[i], aK4[i])]);
      p[0] = pack2(av[i].x, av[i].y); p[1] = pack2(av[i].z, av[i].w);
    }
#pragma unroll
    for (int i=0;i<2;++i){
      unsigned* p = reinterpret_cast<unsigned*>(&lsB[swz_w(bRow[i], bK4[i])]);
      p[0] = pack2(bv[i].x, bv[i].y); p[1] = pack2(bv[i].z, bv[i].w);
    }
    __syncthreads();
    bf16x8 afr[4], bfr[4];
#pragma unroll
    for (int f=0; f<4; ++f) afr[f] = *reinterpret_cast<const bf16x8*>(&lsA[swz_r(wm*64 + f*16 + r16, q)]);
#pragma unroll
    for (int f=0; f<4; ++f) bfr[f] = *reinterpret_cast<const bf16x8*>(&lsB[swz_r(wn*64 + f*16 + r16, q)]);
#pragma unroll
    for (int i=0;i<4;++i)
#pragma unroll
      for (int j=0;j<4;++j)
        acc[i][j] = __builtin_amdgcn_mfma_f32_16x16x32_bf16(afr[i], bfr[j], acc[i][j], 0, 0, 0);
  }

  int sq[4]; float bq[4];
#pragma unroll
  for (int f=0; f<4; ++f){
    int c = colBase + wn*64 + f*16 + r16;
    if (c < NTOK)       { sq[f] = seg_of(c); bq[f] = bias[c]; }
    else if (c < NEXT_) { sq[f] = 0;         bq[f] = cb[c - NTOK]; }
    else                { sq[f] = -1;        bq[f] = 0.f; }
  }
  int sfirst = seg_of(colBase);
  int clast  = colBase + BN - 1; if (clast > NEXT_-1) clast = NEXT_-1;
  int slast  = seg_of(clast);
  int smin = sfirst, smax = slast;
  if (slast < sfirst){ smin = 0; smax = 4; }

#pragma unroll
  for (int i=0;i<4;++i){
#pragma unroll
    for (int r=0;r<4;++r){
      float e[4];
#pragma unroll
      for (int f=0;f<4;++f) e[f] = __expf(acc[i][f][r] + bq[f]);
      int rowg = rowBase + wm*64 + i*16 + (lane>>4)*4 + r;
      for (int s2 = smin; s2 <= smax; ++s2){
        float p = 0.f;
#pragma unroll
        for (int f=0;f<4;++f) p += (sq[f]==s2) ? e[f] : 0.f;
#pragma unroll
        for (int off=1; off<16; off<<=1) p += __shfl_xor(p, off, 16);
        if ((lane & 15) == 0 && p != 0.f) atomicAdd(&accg[rowg*8 + s2], p);
      }
    }
  }
}

// One wave per row: target logit + routing logit + final nll.
__global__ __launch_bounds__(256) void finalize_kernel(
    const float* __restrict__ hidden, const int* __restrict__ target,
    const float* __restrict__ W,      const float* __restrict__ bias,
    const float* __restrict__ cw,     const float* __restrict__ cb,
    const float* __restrict__ accg,   float* __restrict__ out)
{
  const int row  = blockIdx.x * 4 + (threadIdx.x >> 6);
  const int lane = threadIdx.x & 63;
  const int t = target[row];

  const float4* h4 = reinterpret_cast<const float4*>(hidden + (size_t)row * D_DIM);
  const float4* w1 = reinterpret_cast<const float4*>(W + (size_t)t * D_DIM);
  int s = 0; const float* jraw = W; float jb = 0.f;
  if (t >= HEADN){
    if      (t < 20008)  { s=1; jraw = W;          jb = bias[0]; }  // j = 0
    else if (t < 20016)  { s=2; jraw = W + D_DIM;  jb = bias[1]; }  // j = 1
    else if (t < 200000) { s=3; jraw = cw + D_DIM; jb = cb[1];   }  // j = 20001 -> cluster 1
    else                 { s=4; jraw = cw;         jb = cb[0];   }  // j = 20000 -> cluster 0
  }
  const float4* w2 = reinterpret_cast<const float4*>(jraw);

  float p1 = 0.f, p2 = 0.f;
#pragma unroll
  for (int j=0;j<4;++j){
    float4 hv = h4[lane + 64*j];
    float4 av = w1[lane + 64*j];
    float4 bv = w2[lane + 64*j];
    p1 += hv.x*av.x + hv.y*av.y + hv.z*av.z + hv.w*av.w;
    p2 += hv.x*bv.x + hv.y*bv.y + hv.z*bv.z + hv.w*bv.w;
  }
#pragma unroll
  for (int off=32; off; off>>=1){
    p1 += __shfl_xor(p1, off, 64);
    p2 += __shfl_xor(p2, off, 64);
  }

  if (lane == 0){
    float lseH = __logf(accg[row*8 + 0]);
    float nll;
    if (t < HEADN){
      nll = -(p1 + bias[t] - lseH);
    } else {
      float lseS = __logf(accg[row*8 + s]);
      nll = -((p2 + jb - lseH) + (p1 + bias[t] - lseS));
    }
    out[row] = nll;
  }
}

extern "C" void kernel_launch(void* const* d_in, const int* in_sizes, int n_in,
                              void* d_out, int out_size, void* d_ws, size_t ws_size,
                              hipStream_t stream)
{
  const float* hidden = (const float*)d_in[0];
  const int*   target = (const int*)  d_in[1];
  const float* W      = (const float*)d_in[2];
  const float* bias   = (const float*)d_in[3];
  const float* cw     = (const float*)d_in[4];
  const float* cb     = (const float*)d_in[5];
  float* out  = (float*)d_out;
  float* accg = (float*)d_ws;          // [1024][8] fp32 sum-of-exp accumulators

  hipMemsetAsync(accg, 0, 1024*8*sizeof(float), stream);

  if (ws_size >= (size_t)APRIME_OFF + APRIME_BYTES){
    unsigned short* Ap = (unsigned short*)((char*)d_ws + APRIME_OFF);
    prep_convert<<<512, 256, 0, stream>>>(hidden, Ap);
    gemm_lse_adir<<<NBLK, NTHREADS, 0, stream>>>(Ap, W, bias, cw, cb, accg);
  } else {
    gemm_lse_fb<<<NBLK, NTHREADS, 0, stream>>>(hidden, W, bias, cw, cb, accg);
  }
  finalize_kernel<<<256, 256, 0, stream>>>(hidden, target, W, bias, cw, cb, accg, out);
}